// Round 12
// baseline (107.293 us; speedup 1.0000x reference)
//
#include <hip/hip_runtime.h>
#include <math.h>

#define FRAME_LEN 512
#define HOP       256
#define NFREQ     257
#define NBATCH    64
#define NSAMP     160000
#define NSAMPH    80000        // per parity array
#define TFRAMES   624
#define EPS       1.1920928955078125e-07f

#define MT 128                 // frames per tile; 312 M-tiles
#define FT 32                  // freq bins per tile; 5 f-tiles (f 0..128 pad 160)
#define KH 256                 // K per parity
#define TBLKS 160              // table blocks (first, heavy sincosf tail)
#define XBLKS 2500             // x-convert blocks: 16 f32/thread

typedef __attribute__((ext_vector_type(8))) short short8;   // 8 bf16
typedef __attribute__((ext_vector_type(4))) float f32x4;    // MFMA acc

static __device__ __forceinline__ unsigned int f2bf(float f) {
    unsigned int u = __float_as_uint(f);
    return (u + 0x7fffu + ((u >> 16) & 1u)) >> 16;          // RNE to bf16
}

// ---------------- prep: 4 parity tables (first) + x -> bf16 xe/xo -----------
__global__ __launch_bounds__(256) void prep(const float* __restrict__ x,
                                            unsigned short* __restrict__ xe,
                                            unsigned short* __restrict__ xo,
                                            unsigned short* __restrict__ Wec,
                                            unsigned short* __restrict__ Wes,
                                            unsigned short* __restrict__ Woc,
                                            unsigned short* __restrict__ Wos) {
    if (blockIdx.x < TBLKS) {                   // tables [160][256], f<=128 live
        int f = blockIdx.x;                     // 0..159
        int n2 = threadIdx.x;                   // n' 0..255
        unsigned short ec = 0, es = 0, oc = 0, os = 0;
        if (f <= 128) {
            int ne = 2 * n2, no = 2 * n2 + 1;
            float we = 0.5f * (1.0f - cosf(2.0f * (float)M_PI * (float)ne / (float)FRAME_LEN));
            float wo = 0.5f * (1.0f - cosf(2.0f * (float)M_PI * (float)no / (float)FRAME_LEN));
            float ange = (float)((f * ne) & (FRAME_LEN - 1)) * (2.0f * (float)M_PI / (float)FRAME_LEN);
            float ango = (float)((f * no) & (FRAME_LEN - 1)) * (2.0f * (float)M_PI / (float)FRAME_LEN);
            float se_, ce_, so_, co_;
            sincosf(ange, &se_, &ce_);
            sincosf(ango, &so_, &co_);
            ec = (unsigned short)f2bf(ce_ * we);
            es = (unsigned short)f2bf(se_ * we);    // i = +sin*w convention
            oc = (unsigned short)f2bf(co_ * wo);
            os = (unsigned short)f2bf(so_ * wo);
        }
        Wec[f * KH + n2] = ec; Wes[f * KH + n2] = es;
        Woc[f * KH + n2] = oc; Wos[f * KH + n2] = os;
    } else {                                    // 16 f32/thread, parity split
        int i = (blockIdx.x - TBLKS) * 256 + threadIdx.x;
        const float4* src = (const float4*)x + (size_t)i * 4;
        float4 v0 = src[0], v1 = src[1], v2 = src[2], v3 = src[3];
        uint4 e, o;
        e.x = f2bf(v0.x) | (f2bf(v0.z) << 16);
        e.y = f2bf(v1.x) | (f2bf(v1.z) << 16);
        e.z = f2bf(v2.x) | (f2bf(v2.z) << 16);
        e.w = f2bf(v3.x) | (f2bf(v3.z) << 16);
        o.x = f2bf(v0.y) | (f2bf(v0.w) << 16);
        o.y = f2bf(v1.y) | (f2bf(v1.w) << 16);
        o.z = f2bf(v2.y) | (f2bf(v2.w) << 16);
        o.w = f2bf(v3.y) | (f2bf(v3.w) << 16);
        *(uint4*)(xe + (size_t)i * 8) = e;
        *(uint4*)(xo + (size_t)i * 8) = o;
    }
}

// ---- stft: mirror symmetry, ZERO-LDS — MFMA fragments loaded from L2 -------
// A wave's 64 lanes per fragment load touch 16 fully-packed 64B lines
// (lrow -> 16 rows, lhi -> consecutive 16B within a row). Per-XCD working
// set (xe/xo slice 2.5MB + tables 320KB) is L2-resident via XCD swizzle.
// No __shared__, no barriers: waves are fully independent; the unrolled
// K-loop lets the compiler software-pipeline loads across MFMAs freely.
__global__ __launch_bounds__(256) void stft_mfma(
    const unsigned short* __restrict__ xe, const unsigned short* __restrict__ xo,
    const unsigned short* __restrict__ Wec, const unsigned short* __restrict__ Wes,
    const unsigned short* __restrict__ Woc, const unsigned short* __restrict__ Wos,
    float* __restrict__ mag)
{
    const int tid = threadIdx.x;
    // XCD swizzle: nwg=1560=8*195; 5 consecutive logical ids share an A-tile.
    const int logical = ((int)blockIdx.x & 7) * 195 + ((int)blockIdx.x >> 3);
    const int tileM = logical / 5;              // 0..311
    const int tileF = logical % 5;              // 0..4
    const int wid = tid >> 6;
    const int lane = tid & 63;
    const int lrow = lane & 15;
    const int lhi = lane >> 4;

    // k0-invariant fragment base pointers (k folds into imm offset)
    const unsigned short* rowA[2][2];           // [parity][mf]
    #pragma unroll
    for (int mf = 0; mf < 2; mf++) {
        int r = wid * 32 + mf * 16 + lrow;      // row in tile
        int m = tileM * MT + r;                 // < 39936 exact
        int b = m / TFRAMES;
        int t = m - b * TFRAMES;
        size_t off = (size_t)b * NSAMPH + t * (HOP / 2) + lhi * 8;
        rowA[0][mf] = xe + off;
        rowA[1][mf] = xo + off;
    }
    const unsigned short* rowB[2][2][2];        // [parity][cos/sin][nf]
    #pragma unroll
    for (int nf = 0; nf < 2; nf++) {
        int fg = tileF * FT + nf * 16 + lrow;   // < 160 (padded tables)
        size_t off = (size_t)fg * KH + lhi * 8;
        rowB[0][0][nf] = Wec + off; rowB[0][1][nf] = Wes + off;
        rowB[1][0][nf] = Woc + off; rowB[1][1][nf] = Wos + off;
    }

    f32x4 aC[2][2][2] = {};                     // [parity][mf][nf]
    f32x4 aS[2][2][2] = {};

    #pragma unroll
    for (int c = 0; c < 8; c++) {
        const int p = c >> 2;                   // parity (static: unrolled)
        const int k0 = (c & 3) * 64;
        #pragma unroll
        for (int ks = 0; ks < 2; ks++) {
            const int kk = k0 + ks * 32;        // compile-time imm offset
            short8 a[2], bc[2], bs[2];
            #pragma unroll
            for (int mf = 0; mf < 2; mf++)
                a[mf] = *(const short8*)(rowA[p][mf] + kk);
            #pragma unroll
            for (int nf = 0; nf < 2; nf++) {
                bc[nf] = *(const short8*)(rowB[p][0][nf] + kk);
                bs[nf] = *(const short8*)(rowB[p][1][nf] + kk);
            }
            #pragma unroll
            for (int mf = 0; mf < 2; mf++) {
                #pragma unroll
                for (int nf = 0; nf < 2; nf++) {
                    aC[p][mf][nf] = __builtin_amdgcn_mfma_f32_16x16x32_bf16(
                        a[mf], bc[nf], aC[p][mf][nf], 0, 0, 0);
                    aS[p][mf][nf] = __builtin_amdgcn_mfma_f32_16x16x32_bf16(
                        a[mf], bs[nf], aS[p][mf][nf], 0, 0, 0);
                }
            }
        }
    }

    // ---- epilogue: f (<=128) direct, 256-f mirror; float4 over 4 t
    #pragma unroll
    for (int mf = 0; mf < 2; mf++) {
        int m0 = tileM * MT + wid * 32 + mf * 16 + lhi * 4;
        int b = m0 / TFRAMES;
        int t = m0 - b * TFRAMES;               // %4==0, run stays in batch
        #pragma unroll
        for (int nf = 0; nf < 2; nf++) {
            int f = tileF * FT + nf * 16 + lrow;
            float4 od, om;
            #pragma unroll
            for (int q = 0; q < 4; q++) {
                const float Ce = aC[0][mf][nf][q], Co = aC[1][mf][nf][q];
                const float Se = aS[0][mf][nf][q], So = aS[1][mf][nf][q];
                const float rd = Ce + Co, id = Se + So;
                const float rm = Ce - Co, im = So - Se;
                (&od.x)[q] = sqrtf(rd * rd + id * id);
                (&om.x)[q] = sqrtf(rm * rm + im * im);
            }
            if (f <= 128)
                *(float4*)(mag + ((size_t)b * NFREQ + f) * TFRAMES + t) = od;
            if (f <= 127)
                *(float4*)(mag + ((size_t)b * NFREQ + (256 - f)) * TFRAMES + t) = om;
        }
    }
}

// ------------------------------------------- normalize: warp-per-row, f4 ----
__global__ __launch_bounds__(256) void normalize(const float* __restrict__ mag,
                                                 float* __restrict__ feat)
{
    const int row = blockIdx.x * 4 + (threadIdx.x >> 6);    // b*NFREQ+f
    const int lane = threadIdx.x & 63;
    const float* mp = mag + (size_t)row * TFRAMES;

    float4 v[3];
    float sum = 0.f;
    #pragma unroll
    for (int i = 0; i < 3; i++) {
        int c4 = lane + i * 64;                 // 156 float4 per row
        if (c4 < TFRAMES / 4) {
            float4 t = *(const float4*)(mp + c4 * 4);
            t.x = fmaxf(t.x, EPS); t.y = fmaxf(t.y, EPS);
            t.z = fmaxf(t.z, EPS); t.w = fmaxf(t.w, EPS);
            v[i] = t;
            sum += (t.x + t.y) + (t.z + t.w);
        } else {
            v[i] = make_float4(0.f, 0.f, 0.f, 0.f);
        }
    }
    #pragma unroll
    for (int off = 1; off < 64; off <<= 1) sum += __shfl_xor(sum, off, 64);
    const float mean = sum * (1.0f / (float)TFRAMES);

    float ssd = 0.f;
    #pragma unroll
    for (int i = 0; i < 3; i++) {
        int c4 = lane + i * 64;
        if (c4 < TFRAMES / 4) {
            float dx = v[i].x - mean, dy = v[i].y - mean;
            float dz = v[i].z - mean, dw = v[i].w - mean;
            ssd += (dx * dx + dy * dy) + (dz * dz + dw * dw);
        }
    }
    #pragma unroll
    for (int off = 1; off < 64; off <<= 1) ssd += __shfl_xor(ssd, off, 64);
    const float stdv = sqrtf(ssd * (1.0f / (float)(TFRAMES - 1)));
    const float inv = 1.0f / (stdv + EPS);

    float* fp = feat + (size_t)row * TFRAMES;
    #pragma unroll
    for (int i = 0; i < 3; i++) {
        int c4 = lane + i * 64;
        if (c4 < TFRAMES / 4) {
            float4 o;
            o.x = (v[i].x - mean) * inv; o.y = (v[i].y - mean) * inv;
            o.z = (v[i].z - mean) * inv; o.w = (v[i].w - mean) * inv;
            *(float4*)(fp + c4 * 4) = o;
        }
    }
}

// ---------------------------------------------------------------- launch ----
extern "C" void kernel_launch(void* const* d_in, const int* in_sizes, int n_in,
                              void* d_out, int out_size, void* d_ws, size_t ws_size,
                              hipStream_t stream) {
    const float* x = (const float*)d_in[0];
    unsigned short* Wec = (unsigned short*)d_ws;            // [160][256] bf16
    unsigned short* Wes = Wec + 160 * KH;
    unsigned short* Woc = Wes + 160 * KH;
    unsigned short* Wos = Woc + 160 * KH;
    unsigned short* xe  = Wos + 160 * KH;                   // [64][80000] bf16
    unsigned short* xo  = xe + (size_t)NBATCH * NSAMPH;     // [64][80000] bf16
    float* mag  = (float*)d_out;                            // [64][257][624]
    float* feat = mag + (size_t)NBATCH * NFREQ * TFRAMES;

    prep<<<TBLKS + XBLKS, 256, 0, stream>>>(x, xe, xo, Wec, Wes, Woc, Wos);

    // 312 M-tiles x 5 F-tiles, linearized + XCD-swizzled in-kernel
    stft_mfma<<<312 * 5, 256, 0, stream>>>(xe, xo, Wec, Wes, Woc, Wos, mag);

    normalize<<<NBATCH * NFREQ / 4, 256, 0, stream>>>(mag, feat);
}

// Round 13
// 54.471 us; speedup vs baseline: 1.9697x; 1.9697x over previous
//
#include <hip/hip_runtime.h>
#include <math.h>

#define FRAME_LEN 512
#define HOP       256
#define NFREQ     257
#define NBATCH    64
#define NSAMP     160000
#define NSAMPH    80000        // per parity array
#define TFRAMES   624
#define EPS       1.1920928955078125e-07f

#define MT 128                 // frames per tile; 312 M-tiles
#define FT 32                  // freq bins per tile; 5 f-tiles (f 0..128 pad 160)
#define BK 64                  // K chunk per stage
#define KH 256                 // K per parity
#define XBLKS 2560             // x-convert blocks: 40 per batch (ragged tail)

#define ASZ (MT * BK)          // shorts per A buffer (8192)
#define BSZ (2 * FT * BK)      // shorts per B buffer (4096)

typedef __attribute__((ext_vector_type(8))) short short8;   // 8 bf16
typedef __attribute__((ext_vector_type(4))) float f32x4;    // MFMA acc

static __device__ __forceinline__ unsigned int f2bf(float f) {
    unsigned int u = __float_as_uint(f);
    return (u + 0x7fffu + ((u >> 16) & 1u)) >> 16;          // RNE to bf16
}
static __device__ __forceinline__ void gload_lds16(const void* g, void* l) {
    __builtin_amdgcn_global_load_lds(
        (const __attribute__((address_space(1))) void*)g,
        (__attribute__((address_space(3))) void*)l, 16, 0, 0);
}

// -------- prep: x -> bf16 xe/xo with batch<->XCD affinity + parity tables ---
// XCD x (bid&7) converts batches 8x..8x+7 — the same batches stft's XCD x
// consumes — so xe/xo are (partially) L2-resident for stft.
__global__ __launch_bounds__(256) void prep(const float* __restrict__ x,
                                            unsigned short* __restrict__ xe,
                                            unsigned short* __restrict__ xo,
                                            unsigned short* __restrict__ Wec,
                                            unsigned short* __restrict__ Wes,
                                            unsigned short* __restrict__ Woc,
                                            unsigned short* __restrict__ Wos) {
    if (blockIdx.x < XBLKS) {                   // 16 f32/thread, parity split
        const int xcd = blockIdx.x & 7;
        const int slot = blockIdx.x >> 3;       // 0..319
        const int b = xcd * 8 + slot / 40;      // batch, XCD-affine
        const int within = slot % 40;           // 40 blocks/batch
        const int s0 = within * 4096 + threadIdx.x * 16;
        if (s0 + 16 <= NSAMP) {
            const float4* src = (const float4*)(x + (size_t)b * NSAMP + s0);
            float4 v0 = src[0], v1 = src[1], v2 = src[2], v3 = src[3];
            uint4 e, o;
            e.x = f2bf(v0.x) | (f2bf(v0.z) << 16);
            e.y = f2bf(v1.x) | (f2bf(v1.z) << 16);
            e.z = f2bf(v2.x) | (f2bf(v2.z) << 16);
            e.w = f2bf(v3.x) | (f2bf(v3.z) << 16);
            o.x = f2bf(v0.y) | (f2bf(v0.w) << 16);
            o.y = f2bf(v1.y) | (f2bf(v1.w) << 16);
            o.z = f2bf(v2.y) | (f2bf(v2.w) << 16);
            o.w = f2bf(v3.y) | (f2bf(v3.w) << 16);
            size_t off = (size_t)b * NSAMPH + s0 / 2;
            *(uint4*)(xe + off) = e;
            *(uint4*)(xo + off) = o;
        }
    } else {                                    // tables [160][256], f<=128 live
        int f = blockIdx.x - XBLKS;             // 0..159
        int n2 = threadIdx.x;                   // n' 0..255
        unsigned short ec = 0, es = 0, oc = 0, os = 0;
        if (f <= 128) {
            int ne = 2 * n2, no = 2 * n2 + 1;
            float we = 0.5f * (1.0f - cosf(2.0f * (float)M_PI * (float)ne / (float)FRAME_LEN));
            float wo = 0.5f * (1.0f - cosf(2.0f * (float)M_PI * (float)no / (float)FRAME_LEN));
            float ange = (float)((f * ne) & (FRAME_LEN - 1)) * (2.0f * (float)M_PI / (float)FRAME_LEN);
            float ango = (float)((f * no) & (FRAME_LEN - 1)) * (2.0f * (float)M_PI / (float)FRAME_LEN);
            float se_, ce_, so_, co_;
            sincosf(ange, &se_, &ce_);
            sincosf(ango, &so_, &co_);
            ec = (unsigned short)f2bf(ce_ * we);
            es = (unsigned short)f2bf(se_ * we);    // i = +sin*w convention
            oc = (unsigned short)f2bf(co_ * wo);
            os = (unsigned short)f2bf(so_ * wo);
        }
        Wec[f * KH + n2] = ec; Wes[f * KH + n2] = es;
        Woc[f * KH + n2] = oc; Wos[f * KH + n2] = os;
    }
}

// ------ stft via bf16 MFMA + mirror symmetry (r10 structure, unchanged) -----
__global__ __launch_bounds__(256) void stft_mfma(
    const unsigned short* __restrict__ xe, const unsigned short* __restrict__ xo,
    const unsigned short* __restrict__ Wec, const unsigned short* __restrict__ Wes,
    const unsigned short* __restrict__ Woc, const unsigned short* __restrict__ Wos,
    float* __restrict__ mag)
{
    __shared__ unsigned short As[2][MT][BK];    // 32 KB, linear gload dest
    __shared__ unsigned short Bs[2][2][FT][BK]; // 16 KB (cos, sin)

    const int tid = threadIdx.x;
    // XCD swizzle: nwg=1560=8*195; XCD x owns tileM [39x,39x+39) = batches
    // [8x, 8x+8) exactly (39*128 = 8*624); 5 f-tiles per A-tile consecutive.
    const int logical = ((int)blockIdx.x & 7) * 195 + ((int)blockIdx.x >> 3);
    const int tileM = logical / 5;              // 0..311
    const int tileF = logical % 5;              // 0..4
    const int wid = tid >> 6;
    const int lane = tid & 63;
    const int lrow = lane & 15;
    const int lhi = lane >> 4;

    unsigned short* AsB = &As[0][0][0];
    unsigned short* BsB = &Bs[0][0][0][0];

    // k0-invariant per-lane staging sources (XOR chunk swizzle on SOURCE;
    // LDS dest linear for gload_lds; frag read applies the same XOR)
    const unsigned short* pA[2][4];
    #pragma unroll
    for (int j = 0; j < 4; j++) {
        int idx = wid * 4 + j;                  // 0..15, 8 rows each
        int row = idx * 8 + (lane >> 3);
        int m = tileM * MT + row;               // < 39936 exact
        int b = m / TFRAMES;
        int t = m - b * TFRAMES;
        int chunk = (lane & 7) ^ (row & 7);
        size_t off = (size_t)b * NSAMPH + t * (HOP / 2) + chunk * 8;
        pA[0][j] = xe + off;
        pA[1][j] = xo + off;
    }
    const unsigned short* pB[2][2];
    #pragma unroll
    for (int j = 0; j < 2; j++) {
        int i = wid * 2 + j;                    // 0..7: 0-3 cos, 4-7 sin
        int row = (i & 3) * 8 + (lane >> 3);
        int fg = tileF * FT + row;              // < 160 (padded tables)
        int chunk = (lane & 7) ^ (row & 7);
        size_t off = (size_t)fg * KH + chunk * 8;
        pB[0][j] = ((i & 4) ? Wes : Wec) + off;
        pB[1][j] = ((i & 4) ? Wos : Woc) + off;
    }

    f32x4 aC[2][2][2] = {};                     // [parity][mf][nf]
    f32x4 aS[2][2][2] = {};

    // ---- prologue: stage (parity 0, k0=0) into buf 0
    #pragma unroll
    for (int j = 0; j < 4; j++)
        gload_lds16(pA[0][j], AsB + (wid * 4 + j) * 512);
    #pragma unroll
    for (int j = 0; j < 2; j++)
        gload_lds16(pB[0][j], BsB + (wid * 2 + j) * 512);
    __syncthreads();

    int buf = 0;
    #pragma unroll
    for (int it = 0; it < 8; it++) {
        const int p = it >> 2;                  // parity phase (static: unrolled)
        if (it < 7) {
            const int pn = (it + 1) >> 2;
            const int k0 = ((it + 1) & 3) * BK;
            #pragma unroll
            for (int j = 0; j < 4; j++)
                gload_lds16(pA[pn][j] + k0, AsB + (buf ^ 1) * ASZ + (wid * 4 + j) * 512);
            #pragma unroll
            for (int j = 0; j < 2; j++)
                gload_lds16(pB[pn][j] + k0, BsB + (buf ^ 1) * BSZ + (wid * 2 + j) * 512);
        }
        #pragma unroll
        for (int ks = 0; ks < 2; ks++) {
            short8 a[2], bc[2], bsn[2];
            const int c = (ks * 4 + lhi) ^ (lrow & 7);
            #pragma unroll
            for (int mf = 0; mf < 2; mf++)
                a[mf] = *(const short8*)(AsB + buf * ASZ +
                    (wid * 32 + mf * 16 + lrow) * BK + c * 8);
            #pragma unroll
            for (int nf = 0; nf < 2; nf++) {
                bc[nf]  = *(const short8*)(BsB + buf * BSZ +
                    (nf * 16 + lrow) * BK + c * 8);
                bsn[nf] = *(const short8*)(BsB + buf * BSZ + FT * BK +
                    (nf * 16 + lrow) * BK + c * 8);
            }
            #pragma unroll
            for (int mf = 0; mf < 2; mf++) {
                #pragma unroll
                for (int nf = 0; nf < 2; nf++) {
                    aC[p][mf][nf] = __builtin_amdgcn_mfma_f32_16x16x32_bf16(
                        a[mf], bc[nf], aC[p][mf][nf], 0, 0, 0);
                    aS[p][mf][nf] = __builtin_amdgcn_mfma_f32_16x16x32_bf16(
                        a[mf], bsn[nf], aS[p][mf][nf], 0, 0, 0);
                }
            }
        }
        __syncthreads();                        // next buffer landed; reads done
        buf ^= 1;
    }

    // ---- epilogue: f (<=128) direct, 256-f mirror; float4 over 4 t
    #pragma unroll
    for (int mf = 0; mf < 2; mf++) {
        int m0 = tileM * MT + wid * 32 + mf * 16 + lhi * 4;
        int b = m0 / TFRAMES;
        int t = m0 - b * TFRAMES;               // %4==0, run stays in batch
        #pragma unroll
        for (int nf = 0; nf < 2; nf++) {
            int f = tileF * FT + nf * 16 + lrow;
            float4 od, om;
            #pragma unroll
            for (int q = 0; q < 4; q++) {
                const float Ce = aC[0][mf][nf][q], Co = aC[1][mf][nf][q];
                const float Se = aS[0][mf][nf][q], So = aS[1][mf][nf][q];
                const float rd = Ce + Co, id = Se + So;
                const float rm = Ce - Co, im = So - Se;
                (&od.x)[q] = sqrtf(rd * rd + id * id);
                (&om.x)[q] = sqrtf(rm * rm + im * im);
            }
            if (f <= 128)
                *(float4*)(mag + ((size_t)b * NFREQ + f) * TFRAMES + t) = od;
            if (f <= 127)
                *(float4*)(mag + ((size_t)b * NFREQ + (256 - f)) * TFRAMES + t) = om;
        }
    }
}

// ---- normalize: warp-per-row, batch<->XCD affine (reads mag from local L2) -
__global__ __launch_bounds__(256) void normalize(const float* __restrict__ mag,
                                                 float* __restrict__ feat)
{
    // nwg = 4112 = 8*514; XCD x handles rows of batches [8x, 8x+8) — the
    // batches stft's XCD x wrote. 514 = 8 batches * 257 rows / 4 rows-per-blk.
    const int row4 = ((int)blockIdx.x & 7) * 514 + ((int)blockIdx.x >> 3);
    const int row = row4 * 4 + (threadIdx.x >> 6);          // b*NFREQ+f
    const int lane = threadIdx.x & 63;
    const float* mp = mag + (size_t)row * TFRAMES;

    float4 v[3];
    float sum = 0.f;
    #pragma unroll
    for (int i = 0; i < 3; i++) {
        int c4 = lane + i * 64;                 // 156 float4 per row
        if (c4 < TFRAMES / 4) {
            float4 t = *(const float4*)(mp + c4 * 4);
            t.x = fmaxf(t.x, EPS); t.y = fmaxf(t.y, EPS);
            t.z = fmaxf(t.z, EPS); t.w = fmaxf(t.w, EPS);
            v[i] = t;
            sum += (t.x + t.y) + (t.z + t.w);
        } else {
            v[i] = make_float4(0.f, 0.f, 0.f, 0.f);
        }
    }
    #pragma unroll
    for (int off = 1; off < 64; off <<= 1) sum += __shfl_xor(sum, off, 64);
    const float mean = sum * (1.0f / (float)TFRAMES);

    float ssd = 0.f;
    #pragma unroll
    for (int i = 0; i < 3; i++) {
        int c4 = lane + i * 64;
        if (c4 < TFRAMES / 4) {
            float dx = v[i].x - mean, dy = v[i].y - mean;
            float dz = v[i].z - mean, dw = v[i].w - mean;
            ssd += (dx * dx + dy * dy) + (dz * dz + dw * dw);
        }
    }
    #pragma unroll
    for (int off = 1; off < 64; off <<= 1) ssd += __shfl_xor(ssd, off, 64);
    const float stdv = sqrtf(ssd * (1.0f / (float)(TFRAMES - 1)));
    const float inv = 1.0f / (stdv + EPS);

    float* fp = feat + (size_t)row * TFRAMES;
    #pragma unroll
    for (int i = 0; i < 3; i++) {
        int c4 = lane + i * 64;
        if (c4 < TFRAMES / 4) {
            float4 o;
            o.x = (v[i].x - mean) * inv; o.y = (v[i].y - mean) * inv;
            o.z = (v[i].z - mean) * inv; o.w = (v[i].w - mean) * inv;
            *(float4*)(fp + c4 * 4) = o;
        }
    }
}

// ---------------------------------------------------------------- launch ----
extern "C" void kernel_launch(void* const* d_in, const int* in_sizes, int n_in,
                              void* d_out, int out_size, void* d_ws, size_t ws_size,
                              hipStream_t stream) {
    const float* x = (const float*)d_in[0];
    unsigned short* Wec = (unsigned short*)d_ws;            // [160][256] bf16
    unsigned short* Wes = Wec + 160 * KH;
    unsigned short* Woc = Wes + 160 * KH;
    unsigned short* Wos = Woc + 160 * KH;
    unsigned short* xe  = Wos + 160 * KH;                   // [64][80000] bf16
    unsigned short* xo  = xe + (size_t)NBATCH * NSAMPH;     // [64][80000] bf16
    float* mag  = (float*)d_out;                            // [64][257][624]
    float* feat = mag + (size_t)NBATCH * NFREQ * TFRAMES;

    prep<<<XBLKS + 160, 256, 0, stream>>>(x, xe, xo, Wec, Wes, Woc, Wos);

    // 312 M-tiles x 5 F-tiles, linearized + XCD-swizzled in-kernel
    stft_mfma<<<312 * 5, 256, 0, stream>>>(xe, xo, Wec, Wes, Woc, Wos, mag);

    normalize<<<NBATCH * NFREQ / 4, 256, 0, stream>>>(mag, feat);
}